// Round 14
// baseline (100.574 us; speedup 1.0000x reference)
//
#include <hip/hip_runtime.h>
#include <math.h>

typedef __attribute__((ext_vector_type(8))) short bf16x8;
typedef __attribute__((ext_vector_type(16))) float f32x16;
typedef __attribute__((ext_vector_type(4))) float f32x4;

// ws layout (float offsets)
static constexpr size_t WS_WA   = 0;     // 64: wa1[32] ‖ wa2[32] (k0-internal)
static constexpr size_t WS_C12  = 64;    // 2: b.a1, b.a2
static constexpr size_t WS_WMF  = 96;    // 1024 u16: stage-1 B frags [kap][l][e] = wm[t][f], t=16kap+8(l>>5)+e, f=l&31
static constexpr size_t WS_ADJF = 608;   // 1024 u16: stage-2 B frags (adj_n, same layout)
static constexpr size_t WS_WAB  = 1120;  // 1024 u16: s1/s2 B frags: col0=wa1[k], col1=wa2[k], else 0

__device__ __forceinline__ unsigned short f2bf(float x){
    union { float f; unsigned u; } c; c.f = x;
    unsigned r = c.u + 0x7FFFu + ((c.u >> 16) & 1u);
    return (unsigned short)(r >> 16);
}
__device__ __forceinline__ unsigned pk2(float a, float b){
    return (unsigned)f2bf(a) | ((unsigned)f2bf(b) << 16);
}
__device__ __forceinline__ float elu(float x){ return x > 0.f ? x : __expf(x) - 1.0f; }
__device__ __forceinline__ float lrelu(float x){ return fmaxf(x, 0.2f * x); }

__global__ __launch_bounds__(1024) void k0_prep(const float* __restrict__ W_map,
    const float* __restrict__ b_map, const float* __restrict__ a_attn,
    const float* __restrict__ B_adj, float* __restrict__ ws)
{
    __shared__ float lds[1024];
    __shared__ float d12[32];
    __shared__ float waS[64];
    int tid = threadIdx.x;
    int i = tid >> 5, j = tid & 31;
    float a = B_adj[tid] + (i == j ? 1.0f : 0.0f);
    lds[tid] = a; __syncthreads();
    for (int s = 512; s > 0; s >>= 1) { if (tid < s) lds[tid] = fmaxf(lds[tid], lds[tid + s]); __syncthreads(); }
    float mx = lds[0]; __syncthreads();
    lds[tid] = a; __syncthreads();
    for (int s = 512; s > 0; s >>= 1) { if (tid < s) lds[tid] = fminf(lds[tid], lds[tid + s]); __syncthreads(); }
    float mn = lds[0]; __syncthreads();
    lds[tid] = (a - mn) / (mx - mn); __syncthreads();
    if (tid < 32) {
        float s = 0.f;
        for (int jj = 0; jj < 32; ++jj) s += lds[tid * 32 + jj];
        d12[tid] = 1.0f / sqrtf(s);
    }
    if (tid < 32) {
        float w1 = 0.f, w2 = 0.f;
        for (int f = 0; f < 32; ++f) {
            w1 += W_map[tid * 32 + f] * a_attn[f];
            w2 += W_map[tid * 32 + f] * a_attn[32 + f];
        }
        waS[tid] = w1; waS[32 + tid] = w2;
        ws[WS_WA + tid] = w1; ws[WS_WA + 32 + tid] = w2;
    }
    __syncthreads();

    // frag-ordered constants: idx = kap*512 + l*8 + e
    {
        int kap = tid >> 9, rem = tid & 511, l = rem >> 3, e = rem & 7;
        int krow = 16 * kap + 8 * (l >> 5) + e;   // t (for wm) / i (for adj) / k (for wa)
        int col  = l & 31;                        // f / i2
        ((unsigned short*)(ws + WS_WMF))[tid] = f2bf(W_map[krow * 32 + col]);
        float aij = B_adj[krow * 32 + col] + (krow == col ? 1.0f : 0.0f);
        float adjv = d12[krow] * ((aij - mn) / (mx - mn)) * d12[col];
        ((unsigned short*)(ws + WS_ADJF))[tid] = f2bf(adjv);
        float wab = (col == 0) ? waS[krow] : (col == 1) ? waS[32 + krow] : 0.f;
        ((unsigned short*)(ws + WS_WAB))[tid] = f2bf(wab);
    }
    if (tid == 0) {
        float c1 = 0.f, c2 = 0.f;
        for (int f = 0; f < 32; ++f) { c1 += b_map[f] * a_attn[f]; c2 += b_map[f] * a_attn[32 + f]; }
        ws[WS_C12] = c1; ws[WS_C12 + 1] = c2;
    }
}

// D(32x32 mfma, col=l&31) -> next-stage A/B frag (idx=l&31, k=16*KAP+8*(l>>5)+e).
#if __has_builtin(__builtin_amdgcn_permlane32_swap)
typedef __attribute__((ext_vector_type(2))) unsigned int u32p;
template<int KAP>
__device__ __forceinline__ bf16x8 xform(const f32x16& d, int hi){
    (void)hi;
    unsigned b0 = pk2(d[8*KAP+0], d[8*KAP+1]);
    unsigned b1 = pk2(d[8*KAP+2], d[8*KAP+3]);
    unsigned b2 = pk2(d[8*KAP+4], d[8*KAP+5]);
    unsigned b3 = pk2(d[8*KAP+6], d[8*KAP+7]);
    u32p s02 = __builtin_amdgcn_permlane32_swap(b0, b2, false, false);
    u32p s13 = __builtin_amdgcn_permlane32_swap(b1, b3, false, false);
    union { unsigned u[4]; bf16x8 v; } t;
    t.u[0] = s02[0]; t.u[1] = s13[0]; t.u[2] = s02[1]; t.u[3] = s13[1];
    return t.v;
}
#else
template<int KAP>
__device__ __forceinline__ bf16x8 xform(const f32x16& d, int hi){
    unsigned b0 = pk2(d[8*KAP+0], d[8*KAP+1]);
    unsigned b1 = pk2(d[8*KAP+2], d[8*KAP+3]);
    unsigned b2 = pk2(d[8*KAP+4], d[8*KAP+5]);
    unsigned b3 = pk2(d[8*KAP+6], d[8*KAP+7]);
    unsigned pb0 = (unsigned)__shfl_xor((int)b0, 32, 64);
    unsigned pb1 = (unsigned)__shfl_xor((int)b1, 32, 64);
    unsigned pb2 = (unsigned)__shfl_xor((int)b2, 32, 64);
    unsigned pb3 = (unsigned)__shfl_xor((int)b3, 32, 64);
    union { unsigned u[4]; bf16x8 v; } t;
    t.u[0] = hi ? pb2 : b0;
    t.u[1] = hi ? pb3 : b1;
    t.u[2] = hi ? b2 : pb0;
    t.u[3] = hi ? b3 : pb1;
    return t.v;
}
#endif

// Gather one site's A-frags straight from global h.
// Lane l: a0[e]=bf16(h[8*(l>>5)+e][l&31]), a1[e]=bf16(h[16+8*(l>>5)+e][l&31]).
__device__ __forceinline__ void gather_frag(const float* __restrict__ hsite, int l,
                                            bf16x8& a0, bf16x8& a1){
    const int v = l & 31, hw = l >> 5;
    const float* p0 = hsite + (8 * hw) * 32 + v;
    const float* p1 = hsite + (16 + 8 * hw) * 32 + v;
    float x[8], y[8];
#pragma unroll
    for (int e = 0; e < 8; ++e) { x[e] = p0[e * 32]; y[e] = p1[e * 32]; }
    union { unsigned u[4]; bf16x8 v8; } ua, ub;
    ua.u[0] = pk2(x[0], x[1]); ua.u[1] = pk2(x[2], x[3]);
    ua.u[2] = pk2(x[4], x[5]); ua.u[3] = pk2(x[6], x[7]);
    ub.u[0] = pk2(y[0], y[1]); ub.u[1] = pk2(y[2], y[3]);
    ub.u[2] = pk2(y[4], y[5]); ub.u[3] = pk2(y[6], y[7]);
    a0 = ua.v8; a1 = ub.v8;
}

// One block = one (n,hh) row, 512 threads (8 waves, 8 sites/wave).
// h gathered from global ONCE (phase A: s1/s2 MFMA + stage-1 MFMA); Wh frags
// persist in registers (8 sites x 2 x 4 VGPR); LDS only s1/s2/rden (20.5 KB).
// launch_bounds(512,4) caps VGPR at 128 -> 2 blocks/CU co-resident.
__global__ __launch_bounds__(512, 4) void kfused(const float* __restrict__ hin,
    const float* __restrict__ b_map, const float* __restrict__ ws, float* __restrict__ out)
{
    __shared__ float s1L[64 * 32];              // 8 KB  [w][i]
    __shared__ float s2L[64 * 32];              // 8 KB
    __shared__ float rdenL[1024];               // 4 KB  [i][j]

    const int tid = threadIdx.x;
    const int wv = tid >> 6, l = tid & 63;
    const int c = l & 31, hi = l >> 5;
    const int nh = blockIdx.x;                  // n*64 + hh
    const int hh = nh & 63, n = nh >> 6;

    const float c1 = ws[WS_C12], c2 = ws[WS_C12 + 1];
    const float bc = b_map[c];
    const float* hrow = hin + (long)nh * 65536;

    bf16x8 B2f[2];
    {
        const unsigned short* adf = (const unsigned short*)(ws + WS_ADJF);
        B2f[0] = *(const bf16x8*)(adf + l * 8);
        B2f[1] = *(const bf16x8*)(adf + 512 + l * 8);
    }

    bf16x8 A30[8], A31[8];   // persistent Wh frags, one pair per site

    // ---- phase A: gather h once -> s1/s2 MFMA + stage-1 MFMA (Wh -> regs) ----
    {
        bf16x8 B1f[2], WaB[2];
        const unsigned short* wmf = (const unsigned short*)(ws + WS_WMF);
        const unsigned short* wab = (const unsigned short*)(ws + WS_WAB);
        B1f[0] = *(const bf16x8*)(wmf + l * 8);
        B1f[1] = *(const bf16x8*)(wmf + 512 + l * 8);
        WaB[0] = *(const bf16x8*)(wab + l * 8);
        WaB[1] = *(const bf16x8*)(wab + 512 + l * 8);
#pragma unroll
        for (int k = 0; k < 8; ++k) {
            const int s = wv * 8 + k;
            bf16x8 a10, a11;
            gather_frag(hrow + s * 1024, l, a10, a11);
            // s1/s2
            f32x16 ds;
#pragma unroll
            for (int r = 0; r < 16; ++r) ds[r] = 0.f;
            ds = __builtin_amdgcn_mfma_f32_32x32x16_bf16(a10, WaB[0], ds, 0, 0, 0);
            ds = __builtin_amdgcn_mfma_f32_32x32x16_bf16(a11, WaB[1], ds, 0, 0, 0);
            if (c < 2) {
                const float cc = (c == 0) ? c1 : c2;
                float* dst = (c == 0) ? s1L : s2L;
#pragma unroll
                for (int r = 0; r < 16; ++r) {
                    int row = (r & 3) + 8 * (r >> 2) + 4 * hi;
                    dst[s * 32 + row] = ds[r] + cc;
                }
            }
            // stage 1: Wh
            f32x16 d1;
#pragma unroll
            for (int r = 0; r < 16; ++r) d1[r] = bc;
            d1 = __builtin_amdgcn_mfma_f32_32x32x16_bf16(a10, B1f[0], d1, 0, 0, 0);
            d1 = __builtin_amdgcn_mfma_f32_32x32x16_bf16(a11, B1f[1], d1, 0, 0, 0);
            A30[k] = xform<0>(d1, hi);
            A31[k] = xform<1>(d1, hi);
        }
    }
    __syncthreads();

    // ---- phase B: rden[i][j] = 1/sum_w exp(lrelu(s1[w,i]+s2[w,j])), 2/thread ----
    {
#pragma unroll
        for (int p = 0; p < 2; ++p) {
            int idx = p * 512 + tid;
            int i = idx >> 5, j = idx & 31;
            float sum = 0.f;
#pragma unroll
            for (int w = 0; w < 64; ++w)
                sum += __expf(lrelu(s1L[w * 32 + i] + s2L[w * 32 + j]));
            rdenL[idx] = 1.0f / sum;
        }
    }
    __syncthreads();

    // ---- phase C: per site, stages 2+3 from registers, NT stores ----
    const int hh5 = hh >> 5, f3 = hh & 31;
#pragma unroll
    for (int k = 0; k < 8; ++k) {
        const int s = wv * 8 + k;

        // stage 2: D2[j][i2] = sum_i attn[i,j] adj[i,i2]; attn built in-register
        const float s2c = s2L[s * 32 + c];
        f32x4 sa  = *(const f32x4*)&s1L[s * 32 + 8 * hi];
        f32x4 sb  = *(const f32x4*)&s1L[s * 32 + 8 * hi + 4];
        f32x4 sc_ = *(const f32x4*)&s1L[s * 32 + 16 + 8 * hi];
        f32x4 sd  = *(const f32x4*)&s1L[s * 32 + 16 + 8 * hi + 4];
        float q[16];
#pragma unroll
        for (int e = 0; e < 4; ++e) {
            int i0 = 8 * hi + e, i1 = 8 * hi + 4 + e, i2i = 16 + 8 * hi + e, i3 = 16 + 8 * hi + 4 + e;
            q[e]      = __expf(lrelu(sa[e] + s2c))  * rdenL[i0 * 32 + c];
            q[4 + e]  = __expf(lrelu(sb[e] + s2c))  * rdenL[i1 * 32 + c];
            q[8 + e]  = __expf(lrelu(sc_[e] + s2c)) * rdenL[i2i * 32 + c];
            q[12 + e] = __expf(lrelu(sd[e] + s2c))  * rdenL[i3 * 32 + c];
        }
        union { unsigned u[4]; bf16x8 v; } A2_0, A2_1;
        A2_0.u[0] = pk2(q[0], q[1]);   A2_0.u[1] = pk2(q[2], q[3]);
        A2_0.u[2] = pk2(q[4], q[5]);   A2_0.u[3] = pk2(q[6], q[7]);
        A2_1.u[0] = pk2(q[8], q[9]);   A2_1.u[1] = pk2(q[10], q[11]);
        A2_1.u[2] = pk2(q[12], q[13]); A2_1.u[3] = pk2(q[14], q[15]);

        f32x16 d2;
#pragma unroll
        for (int r = 0; r < 16; ++r) d2[r] = 0.f;
        d2 = __builtin_amdgcn_mfma_f32_32x32x16_bf16(A2_0.v, B2f[0], d2, 0, 0, 0);
        d2 = __builtin_amdgcn_mfma_f32_32x32x16_bf16(A2_1.v, B2f[1], d2, 0, 0, 0);
        bf16x8 B3_0 = xform<0>(d2, hi);
        bf16x8 B3_1 = xform<1>(d2, hi);

        // stage 3: D3[f][i2] = sum_j Wh[j][f] M[j][i2]
        f32x16 d3;
#pragma unroll
        for (int r = 0; r < 16; ++r) d3[r] = 0.f;
        d3 = __builtin_amdgcn_mfma_f32_32x32x16_bf16(A30[k], B3_0, d3, 0, 0, 0);
        d3 = __builtin_amdgcn_mfma_f32_32x32x16_bf16(A31[k], B3_1, d3, 0, 0, 0);

        // store: out[(((n*64+w)*64 + f*2+hh5)*32 + f3)*32 + c]
        float* ob = out + (((long)(n * 64 + s) * 64) * 32 + f3) * 32 + c;
#pragma unroll
        for (int r = 0; r < 16; ++r) {
            int f = (r & 3) + 8 * (r >> 2) + 4 * hi;
            __builtin_nontemporal_store(elu(d3[r]), ob + (f * 2 + hh5) * 1024);
        }
    }
}

extern "C" void kernel_launch(void* const* d_in, const int* in_sizes, int n_in,
                              void* d_out, int out_size, void* d_ws, size_t ws_size,
                              hipStream_t stream) {
    (void)in_sizes; (void)n_in; (void)out_size; (void)ws_size;
    const float* hin    = (const float*)d_in[0];
    const float* W_map  = (const float*)d_in[1];
    const float* b_map  = (const float*)d_in[2];
    const float* a_attn = (const float*)d_in[3];
    const float* B_adj  = (const float*)d_in[4];
    float* out = (float*)d_out;
    float* ws  = (float*)d_ws;

    hipLaunchKernelGGL(k0_prep, dim3(1),   dim3(1024), 0, stream, W_map, b_map, a_attn, B_adj, ws);
    hipLaunchKernelGGL(kfused,  dim3(512), dim3(512),  0, stream, hin, b_map, ws, out);
}

// Round 15
// 66.446 us; speedup vs baseline: 1.5136x; 1.5136x over previous
//
#include <hip/hip_runtime.h>
#include <hip/hip_bf16.h>
#include <math.h>

typedef __attribute__((ext_vector_type(8))) short bf16x8;
typedef __attribute__((ext_vector_type(16))) float f32x16;
typedef __attribute__((ext_vector_type(8))) unsigned short us8;

// ws layout (float offsets)
static constexpr size_t WS_WA   = 0;     // 64: wa1[32] ‖ wa2[32] (k0-internal)
static constexpr size_t WS_C12  = 64;    // 2: b.a1, b.a2
static constexpr size_t WS_WMF  = 96;    // 1024 u16: stage-1 B frags [kap][l][e] = wm[t][f]
static constexpr size_t WS_ADJF = 608;   // 1024 u16: stage-2 B frags (adj_n)
static constexpr size_t WS_WAB  = 1120;  // 1024 u16: s1/s2 B frags: col0=wa1, col1=wa2, else 0

__device__ __forceinline__ unsigned short f2bf(float x){
    union { float f; unsigned u; } c; c.f = x;
    unsigned r = c.u + 0x7FFFu + ((c.u >> 16) & 1u);
    return (unsigned short)(r >> 16);
}
// native conversion (RNE) — compiler-known, far fewer VALU ops than bit math
__device__ __forceinline__ unsigned short f2bfn(float x){
    __hip_bfloat16 h = __float2bfloat16(x);
    union { __hip_bfloat16 h; unsigned short u; } cv; cv.h = h; return cv.u;
}
__device__ __forceinline__ unsigned pk2(float a, float b){
    return (unsigned)f2bfn(a) | ((unsigned)f2bfn(b) << 16);
}
__device__ __forceinline__ float bf2f(unsigned short v){
    return __uint_as_float(((unsigned)v) << 16);
}
__device__ __forceinline__ float elu(float x){ return x > 0.f ? x : __expf(x) - 1.0f; }
__device__ __forceinline__ float lrelu(float x){ return fmaxf(x, 0.2f * x); }

__global__ __launch_bounds__(1024) void k0_prep(const float* __restrict__ W_map,
    const float* __restrict__ b_map, const float* __restrict__ a_attn,
    const float* __restrict__ B_adj, float* __restrict__ ws)
{
    __shared__ float lds[1024];
    __shared__ float d12[32];
    __shared__ float waS[64];
    int tid = threadIdx.x;
    int i = tid >> 5, j = tid & 31;
    float a = B_adj[tid] + (i == j ? 1.0f : 0.0f);
    lds[tid] = a; __syncthreads();
    for (int s = 512; s > 0; s >>= 1) { if (tid < s) lds[tid] = fmaxf(lds[tid], lds[tid + s]); __syncthreads(); }
    float mx = lds[0]; __syncthreads();
    lds[tid] = a; __syncthreads();
    for (int s = 512; s > 0; s >>= 1) { if (tid < s) lds[tid] = fminf(lds[tid], lds[tid + s]); __syncthreads(); }
    float mn = lds[0]; __syncthreads();
    lds[tid] = (a - mn) / (mx - mn); __syncthreads();
    if (tid < 32) {
        float s = 0.f;
        for (int jj = 0; jj < 32; ++jj) s += lds[tid * 32 + jj];
        d12[tid] = 1.0f / sqrtf(s);
    }
    if (tid < 32) {
        float w1 = 0.f, w2 = 0.f;
        for (int f = 0; f < 32; ++f) {
            w1 += W_map[tid * 32 + f] * a_attn[f];
            w2 += W_map[tid * 32 + f] * a_attn[32 + f];
        }
        waS[tid] = w1; waS[32 + tid] = w2;
        ws[WS_WA + tid] = w1; ws[WS_WA + 32 + tid] = w2;
    }
    __syncthreads();
    {
        int kap = tid >> 9, rem = tid & 511, l = rem >> 3, e = rem & 7;
        int krow = 16 * kap + 8 * (l >> 5) + e;
        int col  = l & 31;
        ((unsigned short*)(ws + WS_WMF))[tid] = f2bf(W_map[krow * 32 + col]);
        float aij = B_adj[krow * 32 + col] + (krow == col ? 1.0f : 0.0f);
        float adjv = d12[krow] * ((aij - mn) / (mx - mn)) * d12[col];
        ((unsigned short*)(ws + WS_ADJF))[tid] = f2bf(adjv);
        float wab = (col == 0) ? waS[krow] : (col == 1) ? waS[32 + krow] : 0.f;
        ((unsigned short*)(ws + WS_WAB))[tid] = f2bf(wab);
    }
    if (tid == 0) {
        float c1 = 0.f, c2 = 0.f;
        for (int f = 0; f < 32; ++f) { c1 += b_map[f] * a_attn[f]; c2 += b_map[f] * a_attn[32 + f]; }
        ws[WS_C12] = c1; ws[WS_C12 + 1] = c2;
    }
}

// D(32x32 mfma, col=l&31) -> next-stage A/B frag (idx=l&31, k=16*KAP+8*(l>>5)+e).
#if __has_builtin(__builtin_amdgcn_permlane32_swap)
typedef __attribute__((ext_vector_type(2))) unsigned int u32p;
template<int KAP>
__device__ __forceinline__ bf16x8 xform(const f32x16& d, int hi){
    (void)hi;
    unsigned b0 = pk2(d[8*KAP+0], d[8*KAP+1]);
    unsigned b1 = pk2(d[8*KAP+2], d[8*KAP+3]);
    unsigned b2 = pk2(d[8*KAP+4], d[8*KAP+5]);
    unsigned b3 = pk2(d[8*KAP+6], d[8*KAP+7]);
    u32p s02 = __builtin_amdgcn_permlane32_swap(b0, b2, false, false);
    u32p s13 = __builtin_amdgcn_permlane32_swap(b1, b3, false, false);
    union { unsigned u[4]; bf16x8 v; } t;
    t.u[0] = s02[0]; t.u[1] = s13[0]; t.u[2] = s02[1]; t.u[3] = s13[1];
    return t.v;
}
#else
template<int KAP>
__device__ __forceinline__ bf16x8 xform(const f32x16& d, int hi){
    unsigned b0 = pk2(d[8*KAP+0], d[8*KAP+1]);
    unsigned b1 = pk2(d[8*KAP+2], d[8*KAP+3]);
    unsigned b2 = pk2(d[8*KAP+4], d[8*KAP+5]);
    unsigned b3 = pk2(d[8*KAP+6], d[8*KAP+7]);
    unsigned pb0 = (unsigned)__shfl_xor((int)b0, 32, 64);
    unsigned pb1 = (unsigned)__shfl_xor((int)b1, 32, 64);
    unsigned pb2 = (unsigned)__shfl_xor((int)b2, 32, 64);
    unsigned pb3 = (unsigned)__shfl_xor((int)b3, 32, 64);
    union { unsigned u[4]; bf16x8 v; } t;
    t.u[0] = hi ? pb2 : b0;
    t.u[1] = hi ? pb3 : b1;
    t.u[2] = hi ? b2 : pb0;
    t.u[3] = hi ? b3 : pb1;
    return t.v;
}
#endif

// raw gather of one site's frag values (16 stride-32 loads, 128B-coalesced)
__device__ __forceinline__ void gather_raw(const float* __restrict__ hsite, int l,
                                           float* __restrict__ x, float* __restrict__ y){
    const int v = l & 31, hw = l >> 5;
    const float* p0 = hsite + (8 * hw) * 32 + v;
    const float* p1 = hsite + (16 + 8 * hw) * 32 + v;
#pragma unroll
    for (int e = 0; e < 8; ++e) { x[e] = p0[e * 32]; y[e] = p1[e * 32]; }
}
__device__ __forceinline__ bf16x8 pack8(const float* __restrict__ x){
    union { unsigned u[4]; bf16x8 v8; } t;
    t.u[0] = pk2(x[0], x[1]); t.u[1] = pk2(x[2], x[3]);
    t.u[2] = pk2(x[4], x[5]); t.u[3] = pk2(x[6], x[7]);
    return t.v8;
}

// s1/s2 MFMA for one site from its frags; lanes c<2 write bf16 rows
__device__ __forceinline__ void s12_mfma(bf16x8 a10, bf16x8 a11, const bf16x8* WaB,
    unsigned short* s1p, unsigned short* s2p, int s, int c, int hi, float c1, float c2)
{
    f32x16 ds;
#pragma unroll
    for (int r = 0; r < 16; ++r) ds[r] = 0.f;
    ds = __builtin_amdgcn_mfma_f32_32x32x16_bf16(a10, WaB[0], ds, 0, 0, 0);
    ds = __builtin_amdgcn_mfma_f32_32x32x16_bf16(a11, WaB[1], ds, 0, 0, 0);
    if (c < 2) {
        const float cc = (c == 0) ? c1 : c2;
        unsigned short* dst = (c == 0) ? s1p : s2p;
#pragma unroll
        for (int r = 0; r < 16; ++r) {
            int row = (r & 3) + 8 * (r >> 2) + 4 * hi;
            dst[s * 32 + row] = f2bfn(ds[r] + cc);
        }
    }
}

// full per-site compute (stages 1-3) + NT store for row nh
__device__ __forceinline__ void site_compute(const unsigned short* __restrict__ hbf,
    const unsigned short* __restrict__ s1p, const unsigned short* __restrict__ s2p,
    const float* __restrict__ rdenL, float* __restrict__ out,
    int nh, int s, int l, int c, int hi, const bf16x8* B1f, const bf16x8* B2f, float bc)
{
    const bf16x8 a10 = *(const bf16x8*)(hbf + s * 1024 + l * 8);
    const bf16x8 a11 = *(const bf16x8*)(hbf + s * 1024 + 512 + l * 8);

    // stage 1: D1[j][f] = sum_t h[t][j] wm[t][f] + b[f]
    f32x16 d1;
#pragma unroll
    for (int r = 0; r < 16; ++r) d1[r] = bc;
    d1 = __builtin_amdgcn_mfma_f32_32x32x16_bf16(a10, B1f[0], d1, 0, 0, 0);
    d1 = __builtin_amdgcn_mfma_f32_32x32x16_bf16(a11, B1f[1], d1, 0, 0, 0);
    bf16x8 A3_0 = xform<0>(d1, hi);
    bf16x8 A3_1 = xform<1>(d1, hi);

    // stage 2: attn in-register from bf16 s1/s2 + rden
    const us8 s1a = *(const us8*)(s1p + s * 32 + 8 * hi);
    const us8 s1c = *(const us8*)(s1p + s * 32 + 16 + 8 * hi);
    const float s2c = bf2f(s2p[s * 32 + c]);
    float q[16];
#pragma unroll
    for (int e = 0; e < 4; ++e) {
        q[e]      = __expf(lrelu(bf2f(s1a[e])     + s2c)) * rdenL[(8 * hi + e) * 32 + c];
        q[4 + e]  = __expf(lrelu(bf2f(s1a[4 + e]) + s2c)) * rdenL[(8 * hi + 4 + e) * 32 + c];
        q[8 + e]  = __expf(lrelu(bf2f(s1c[e])     + s2c)) * rdenL[(16 + 8 * hi + e) * 32 + c];
        q[12 + e] = __expf(lrelu(bf2f(s1c[4 + e]) + s2c)) * rdenL[(16 + 8 * hi + 4 + e) * 32 + c];
    }
    union { unsigned u[4]; bf16x8 v; } A2_0, A2_1;
    A2_0.u[0] = pk2(q[0], q[1]);   A2_0.u[1] = pk2(q[2], q[3]);
    A2_0.u[2] = pk2(q[4], q[5]);   A2_0.u[3] = pk2(q[6], q[7]);
    A2_1.u[0] = pk2(q[8], q[9]);   A2_1.u[1] = pk2(q[10], q[11]);
    A2_1.u[2] = pk2(q[12], q[13]); A2_1.u[3] = pk2(q[14], q[15]);

    f32x16 d2;
#pragma unroll
    for (int r = 0; r < 16; ++r) d2[r] = 0.f;
    d2 = __builtin_amdgcn_mfma_f32_32x32x16_bf16(A2_0.v, B2f[0], d2, 0, 0, 0);
    d2 = __builtin_amdgcn_mfma_f32_32x32x16_bf16(A2_1.v, B2f[1], d2, 0, 0, 0);
    bf16x8 B3_0 = xform<0>(d2, hi);
    bf16x8 B3_1 = xform<1>(d2, hi);

    // stage 3
    f32x16 d3;
#pragma unroll
    for (int r = 0; r < 16; ++r) d3[r] = 0.f;
    d3 = __builtin_amdgcn_mfma_f32_32x32x16_bf16(A3_0, B3_0, d3, 0, 0, 0);
    d3 = __builtin_amdgcn_mfma_f32_32x32x16_bf16(A3_1, B3_1, d3, 0, 0, 0);

    const int hh = nh & 63, n = nh >> 6, hh5 = hh >> 5, f3 = hh & 31;
    float* ob = out + (((long)(n * 64 + s) * 64) * 32 + f3) * 32 + c;
#pragma unroll
    for (int r = 0; r < 16; ++r) {
        int f = (r & 3) + 8 * (r >> 2) + 4 * hi;
        __builtin_nontemporal_store(elu(d3[r]), ob + (f * 2 + hh5) * 1024);
    }
}

// One block = TWO (n,hh) rows. hbf slots are wave-private -> no barrier on hbf.
// While computing/storing row r0's sites, row r1's gathers are in flight (T14).
__global__ __launch_bounds__(1024) void kfused(const float* __restrict__ hin,
    const float* __restrict__ b_map, const float* __restrict__ ws, float* __restrict__ out)
{
    __shared__ unsigned short hbf[64 * 1024];   // 128 KB, per-site 1KB, wave-private
    __shared__ unsigned short s1b[2][2048];     // 8 KB bf16 (two rows)
    __shared__ unsigned short s2b[2][2048];     // 8 KB
    __shared__ float rdenL[1024];               // 4 KB (reused r0 -> r1)

    const int tid = threadIdx.x;
    const int wv = tid >> 6, l = tid & 63;
    const int c = l & 31, hi = l >> 5;
    const int nh0 = blockIdx.x * 2, nh1 = nh0 + 1;

    const float c1 = ws[WS_C12], c2 = ws[WS_C12 + 1];
    const float bc = b_map[c];
    const float* hrow0 = hin + (long)nh0 * 65536;
    const float* hrow1 = hin + (long)nh1 * 65536;

    bf16x8 B1f[2], B2f[2], WaB[2];
    {
        const unsigned short* wmf = (const unsigned short*)(ws + WS_WMF);
        const unsigned short* adf = (const unsigned short*)(ws + WS_ADJF);
        const unsigned short* wab = (const unsigned short*)(ws + WS_WAB);
        B1f[0] = *(const bf16x8*)(wmf + l * 8);
        B1f[1] = *(const bf16x8*)(wmf + 512 + l * 8);
        B2f[0] = *(const bf16x8*)(adf + l * 8);
        B2f[1] = *(const bf16x8*)(adf + 512 + l * 8);
        WaB[0] = *(const bf16x8*)(wab + l * 8);
        WaB[1] = *(const bf16x8*)(wab + 512 + l * 8);
    }

    // ---- A(r0): per wave, gather own 4 sites -> hbf + s1/s2 MFMA ----
#pragma unroll
    for (int k = 0; k < 4; ++k) {
        const int s = wv * 4 + k;
        float x[8], y[8];
        gather_raw(hrow0 + s * 1024, l, x, y);
        bf16x8 a10 = pack8(x), a11 = pack8(y);
        *(bf16x8*)(hbf + s * 1024 + l * 8) = a10;
        *(bf16x8*)(hbf + s * 1024 + 512 + l * 8) = a11;
        s12_mfma(a10, a11, WaB, s1b[0], s2b[0], s, c, hi, c1, c2);
    }
    __syncthreads();

    // ---- B(r0) ----
    {
        int i = tid >> 5, j = tid & 31;
        float sum = 0.f;
#pragma unroll
        for (int w = 0; w < 64; ++w)
            sum += __expf(lrelu(bf2f(s1b[0][w * 32 + i]) + bf2f(s2b[0][w * 32 + j])));
        rdenL[tid] = 1.0f / sum;
    }
    __syncthreads();

    // ---- C(r0) with A(r1) prefetch overlapped ----
#pragma unroll
    for (int k = 0; k < 4; ++k) {
        const int s = wv * 4 + k;
        float px[8], py[8];
        gather_raw(hrow1 + s * 1024, l, px, py);            // issue loads early
        site_compute(hbf, s1b[0], s2b[0], rdenL, out, nh0, s, l, c, hi, B1f, B2f, bc);
        bf16x8 pa10 = pack8(px), pa11 = pack8(py);          // consume late
        *(bf16x8*)(hbf + s * 1024 + l * 8) = pa10;          // own slot, already read
        *(bf16x8*)(hbf + s * 1024 + 512 + l * 8) = pa11;
        s12_mfma(pa10, pa11, WaB, s1b[1], s2b[1], s, c, hi, c1, c2);
    }
    __syncthreads();

    // ---- B(r1) ----
    {
        int i = tid >> 5, j = tid & 31;
        float sum = 0.f;
#pragma unroll
        for (int w = 0; w < 64; ++w)
            sum += __expf(lrelu(bf2f(s1b[1][w * 32 + i]) + bf2f(s2b[1][w * 32 + j])));
        rdenL[tid] = 1.0f / sum;
    }
    __syncthreads();

    // ---- C(r1), no prefetch ----
#pragma unroll
    for (int k = 0; k < 4; ++k) {
        const int s = wv * 4 + k;
        site_compute(hbf, s1b[1], s2b[1], rdenL, out, nh1, s, l, c, hi, B1f, B2f, bc);
    }
}

extern "C" void kernel_launch(void* const* d_in, const int* in_sizes, int n_in,
                              void* d_out, int out_size, void* d_ws, size_t ws_size,
                              hipStream_t stream) {
    (void)in_sizes; (void)n_in; (void)out_size; (void)ws_size;
    const float* hin    = (const float*)d_in[0];
    const float* W_map  = (const float*)d_in[1];
    const float* b_map  = (const float*)d_in[2];
    const float* a_attn = (const float*)d_in[3];
    const float* B_adj  = (const float*)d_in[4];
    float* out = (float*)d_out;
    float* ws  = (float*)d_ws;

    hipLaunchKernelGGL(k0_prep, dim3(1),   dim3(1024), 0, stream, W_map, b_map, a_attn, B_adj, ws);
    hipLaunchKernelGGL(kfused,  dim3(256), dim3(1024), 0, stream, hin, b_map, ws, out);
}

// Round 17
// 64.644 us; speedup vs baseline: 1.5558x; 1.0279x over previous
//
#include <hip/hip_runtime.h>
#include <math.h>

typedef __attribute__((ext_vector_type(8))) short bf16x8;
typedef __attribute__((ext_vector_type(16))) float f32x16;
typedef __attribute__((ext_vector_type(4))) float f32x4;
typedef __attribute__((ext_vector_type(8))) unsigned short us8;

#define LOG2E 1.4426950408889634f

// ws layout (float offsets)
static constexpr size_t WS_WA   = 0;     // 64: wa1[32] ‖ wa2[32] (k0-internal)
static constexpr size_t WS_C12  = 64;    // 2: (b.a1)*log2e, (b.a2)*log2e
static constexpr size_t WS_WMF  = 96;    // 1024 u16: stage-1 B frags [kap][l][e] = wm[t][f], t=16kap+8(l>>5)+e, f=l&31
static constexpr size_t WS_ADJF = 608;   // 1024 u16: stage-2 B frags (adj_n, same layout)
static constexpr size_t WS_WAB  = 1120;  // 1024 u16: s1/s2 B frags (pre-scaled by log2e): col0=wa1, col1=wa2, else 0

// native 2^x / log2(x) (v_exp_f32 / v_log_f32)
__device__ __forceinline__ float exp2v(float x){ return __builtin_amdgcn_exp2f(x); }
__device__ __forceinline__ float log2v(float x){ return __builtin_amdgcn_logf(x); }

__device__ __forceinline__ unsigned short f2bf(float x){
    union { float f; unsigned u; } c; c.f = x;
    unsigned r = c.u + 0x7FFFu + ((c.u >> 16) & 1u);
    return (unsigned short)(r >> 16);
}
__device__ __forceinline__ unsigned pk2(float a, float b){
    return (unsigned)f2bf(a) | ((unsigned)f2bf(b) << 16);
}
__device__ __forceinline__ float bf2f(unsigned short v){
    return __uint_as_float(((unsigned)v) << 16);
}
__device__ __forceinline__ float elu(float x){ return x > 0.f ? x : __expf(x) - 1.0f; }
__device__ __forceinline__ float lrelu(float x){ return fmaxf(x, 0.2f * x); }

__global__ __launch_bounds__(1024) void k0_prep(const float* __restrict__ W_map,
    const float* __restrict__ b_map, const float* __restrict__ a_attn,
    const float* __restrict__ B_adj, float* __restrict__ ws)
{
    __shared__ float lds[1024];
    __shared__ float d12[32];
    __shared__ float waS[64];
    int tid = threadIdx.x;
    int i = tid >> 5, j = tid & 31;
    float a = B_adj[tid] + (i == j ? 1.0f : 0.0f);
    lds[tid] = a; __syncthreads();
    for (int s = 512; s > 0; s >>= 1) { if (tid < s) lds[tid] = fmaxf(lds[tid], lds[tid + s]); __syncthreads(); }
    float mx = lds[0]; __syncthreads();
    lds[tid] = a; __syncthreads();
    for (int s = 512; s > 0; s >>= 1) { if (tid < s) lds[tid] = fminf(lds[tid], lds[tid + s]); __syncthreads(); }
    float mn = lds[0]; __syncthreads();
    lds[tid] = (a - mn) / (mx - mn); __syncthreads();
    if (tid < 32) {
        float s = 0.f;
        for (int jj = 0; jj < 32; ++jj) s += lds[tid * 32 + jj];
        d12[tid] = 1.0f / sqrtf(s);
    }
    if (tid < 32) {
        float w1 = 0.f, w2 = 0.f;
        for (int f = 0; f < 32; ++f) {
            w1 += W_map[tid * 32 + f] * a_attn[f];
            w2 += W_map[tid * 32 + f] * a_attn[32 + f];
        }
        waS[tid] = w1; waS[32 + tid] = w2;
        ws[WS_WA + tid] = w1; ws[WS_WA + 32 + tid] = w2;
    }
    __syncthreads();

    // frag-ordered constants: idx = kap*512 + l*8 + e
    {
        int kap = tid >> 9, rem = tid & 511, l = rem >> 3, e = rem & 7;
        int krow = 16 * kap + 8 * (l >> 5) + e;   // t (for wm) / i (for adj) / k (for wa)
        int col  = l & 31;                        // f / i2
        ((unsigned short*)(ws + WS_WMF))[tid] = f2bf(W_map[krow * 32 + col]);
        float aij = B_adj[krow * 32 + col] + (krow == col ? 1.0f : 0.0f);
        float adjv = d12[krow] * ((aij - mn) / (mx - mn)) * d12[col];
        ((unsigned short*)(ws + WS_ADJF))[tid] = f2bf(adjv);
        // pre-scale by log2e: downstream softmax runs in log2 domain
        float wab = (col == 0) ? waS[krow] * LOG2E : (col == 1) ? waS[32 + krow] * LOG2E : 0.f;
        ((unsigned short*)(ws + WS_WAB))[tid] = f2bf(wab);
    }
    if (tid == 0) {
        float c1 = 0.f, c2 = 0.f;
        for (int f = 0; f < 32; ++f) { c1 += b_map[f] * a_attn[f]; c2 += b_map[f] * a_attn[32 + f]; }
        ws[WS_C12] = c1 * LOG2E; ws[WS_C12 + 1] = c2 * LOG2E;
    }
}

// D(32x32 mfma, col=l&31) -> next-stage A/B frag (idx=l&31, k=16*KAP+8*(l>>5)+e).
#if __has_builtin(__builtin_amdgcn_permlane32_swap)
typedef __attribute__((ext_vector_type(2))) unsigned int u32p;
template<int KAP>
__device__ __forceinline__ bf16x8 xform(const f32x16& d, int hi){
    (void)hi;
    unsigned b0 = pk2(d[8*KAP+0], d[8*KAP+1]);
    unsigned b1 = pk2(d[8*KAP+2], d[8*KAP+3]);
    unsigned b2 = pk2(d[8*KAP+4], d[8*KAP+5]);
    unsigned b3 = pk2(d[8*KAP+6], d[8*KAP+7]);
    u32p s02 = __builtin_amdgcn_permlane32_swap(b0, b2, false, false);
    u32p s13 = __builtin_amdgcn_permlane32_swap(b1, b3, false, false);
    union { unsigned u[4]; bf16x8 v; } t;
    t.u[0] = s02[0]; t.u[1] = s13[0]; t.u[2] = s02[1]; t.u[3] = s13[1];
    return t.v;
}
#else
template<int KAP>
__device__ __forceinline__ bf16x8 xform(const f32x16& d, int hi){
    unsigned b0 = pk2(d[8*KAP+0], d[8*KAP+1]);
    unsigned b1 = pk2(d[8*KAP+2], d[8*KAP+3]);
    unsigned b2 = pk2(d[8*KAP+4], d[8*KAP+5]);
    unsigned b3 = pk2(d[8*KAP+6], d[8*KAP+7]);
    unsigned pb0 = (unsigned)__shfl_xor((int)b0, 32, 64);
    unsigned pb1 = (unsigned)__shfl_xor((int)b1, 32, 64);
    unsigned pb2 = (unsigned)__shfl_xor((int)b2, 32, 64);
    unsigned pb3 = (unsigned)__shfl_xor((int)b3, 32, 64);
    union { unsigned u[4]; bf16x8 v; } t;
    t.u[0] = hi ? pb2 : b0;
    t.u[1] = hi ? pb3 : b1;
    t.u[2] = hi ? b2 : pb0;
    t.u[3] = hi ? b3 : pb1;
    return t.v;
}
#endif

// One block = one (n,hh) row. h staged once (bf16 frag order, conflict-free);
// s1/s2 via MFMA (log2-scaled); rden as -log2(den); 3 chained MFMA stages; NT stores.
__global__ __launch_bounds__(1024, 4) void kfused(const float* __restrict__ hin,
    const float* __restrict__ b_map, const float* __restrict__ ws, float* __restrict__ out)
{
    __shared__ unsigned short hbf[64 * 1024];   // 128 KB: [s][kap][v+32hw][e]
    __shared__ float s1L[64 * 32];              // 8 KB  [w][i]  (log2-scaled)
    __shared__ float s2L[64 * 32];              // 8 KB
    __shared__ float rdenL[1024];               // 4 KB  [i][j] = -log2(den)

    const int tid = threadIdx.x;
    const int wv = tid >> 6, l = tid & 63;
    const int c = l & 31, hi = l >> 5;
    const int nh = blockIdx.x;                  // n*64 + hh
    const int hh = nh & 63, n = nh >> 6;

    const float c1 = ws[WS_C12], c2 = ws[WS_C12 + 1];
    const float bc = b_map[c];

    bf16x8 B1f[2], B2f[2], WaB[2];
    {
        const unsigned short* wmf = (const unsigned short*)(ws + WS_WMF);
        const unsigned short* adf = (const unsigned short*)(ws + WS_ADJF);
        const unsigned short* wab = (const unsigned short*)(ws + WS_WAB);
        B1f[0] = *(const bf16x8*)(wmf + l * 8);
        B1f[1] = *(const bf16x8*)(wmf + 512 + l * 8);
        B2f[0] = *(const bf16x8*)(adf + l * 8);
        B2f[1] = *(const bf16x8*)(adf + 512 + l * 8);
        WaB[0] = *(const bf16x8*)(wab + l * 8);
        WaB[1] = *(const bf16x8*)(wab + 512 + l * 8);
    }

    // ---- phase A: stage row -> hbf. 8 stride-32 scalar loads (128B coalesced)
    // -> one contiguous ds_write_b128. Zero conflicts. ----
    {
        const float* hrow = hin + (long)nh * 65536;
        const int v = tid & 31;
#pragma unroll
        for (int it = 0; it < 8; ++it) {
            const int gid = it * 32 + (tid >> 5);           // 0..255
            const int site = gid >> 2, kap = (gid >> 1) & 1, hw = gid & 1;
            const float* hp = hrow + site * 1024 + (16 * kap + 8 * hw) * 32 + v;
            float x[8];
#pragma unroll
            for (int e = 0; e < 8; ++e) x[e] = hp[e * 32];
            union { unsigned u[4]; us8 v8; } pk;
            pk.u[0] = pk2(x[0], x[1]); pk.u[1] = pk2(x[2], x[3]);
            pk.u[2] = pk2(x[4], x[5]); pk.u[3] = pk2(x[6], x[7]);
            *(us8*)(hbf + site * 1024 + kap * 512 + (v + 32 * hw) * 8) = pk.v8;
        }
    }
    __syncthreads();

    // ---- phase A2: s1/s2 via MFMA (log2-scaled). Lanes c<2 write to s1L/s2L. ----
    {
#pragma unroll
        for (int k = 0; k < 4; ++k) {
            const int s = wv * 4 + k;
            const unsigned short* fp = hbf + s * 1024;
            bf16x8 a10 = *(const bf16x8*)(fp + l * 8);
            bf16x8 a11 = *(const bf16x8*)(fp + 512 + l * 8);
            f32x16 ds;
#pragma unroll
            for (int r = 0; r < 16; ++r) ds[r] = 0.f;
            ds = __builtin_amdgcn_mfma_f32_32x32x16_bf16(a10, WaB[0], ds, 0, 0, 0);
            ds = __builtin_amdgcn_mfma_f32_32x32x16_bf16(a11, WaB[1], ds, 0, 0, 0);
            if (c < 2) {
                const float cc = (c == 0) ? c1 : c2;
                float* dst = (c == 0) ? s1L : s2L;
#pragma unroll
                for (int r = 0; r < 16; ++r) {
                    int row = (r & 3) + 8 * (r >> 2) + 4 * hi;
                    dst[s * 32 + row] = ds[r] + cc;
                }
            }
        }
    }
    __syncthreads();

    // ---- phase B: rden[i][j] = -log2( sum_w 2^lrelu(s1'[w,i]+s2'[w,j]) ) ----
    {
        int i = tid >> 5, j = tid & 31;
        float sum = 0.f;
#pragma unroll
        for (int w = 0; w < 64; ++w)
            sum += exp2v(lrelu(s1L[w * 32 + i] + s2L[w * 32 + j]));
        rdenL[tid] = -log2v(sum);
    }
    __syncthreads();

    // ---- phase C: per site, 3 chained 32x32 matmuls, NT stores ----
    const int hh5 = hh >> 5, f3 = hh & 31;
#pragma unroll 2
    for (int k = 0; k < 4; ++k) {
        const int s = wv * 4 + k;
        const unsigned short* fp = hbf + s * 1024;
        bf16x8 a10 = *(const bf16x8*)(fp + l * 8);
        bf16x8 a11 = *(const bf16x8*)(fp + 512 + l * 8);

        // stage 1: D1[j][f] = sum_t h[t][j] wm[t][f] + b[f]
        f32x16 d1;
#pragma unroll
        for (int r = 0; r < 16; ++r) d1[r] = bc;
        d1 = __builtin_amdgcn_mfma_f32_32x32x16_bf16(a10, B1f[0], d1, 0, 0, 0);
        d1 = __builtin_amdgcn_mfma_f32_32x32x16_bf16(a11, B1f[1], d1, 0, 0, 0);
        bf16x8 A3_0 = xform<0>(d1, hi);
        bf16x8 A3_1 = xform<1>(d1, hi);

        // stage 2: attn = 2^( lrelu(s1'+s2') + lrden )  (all log2-domain)
        const float s2c = s2L[s * 32 + c];
        f32x4 sa  = *(const f32x4*)&s1L[s * 32 + 8 * hi];
        f32x4 sb  = *(const f32x4*)&s1L[s * 32 + 8 * hi + 4];
        f32x4 sc_ = *(const f32x4*)&s1L[s * 32 + 16 + 8 * hi];
        f32x4 sd  = *(const f32x4*)&s1L[s * 32 + 16 + 8 * hi + 4];
        float q[16];
#pragma unroll
        for (int e = 0; e < 4; ++e) {
            int i0 = 8 * hi + e, i1 = 8 * hi + 4 + e, i2i = 16 + 8 * hi + e, i3 = 16 + 8 * hi + 4 + e;
            q[e]      = exp2v(lrelu(sa[e] + s2c)  + rdenL[i0 * 32 + c]);
            q[4 + e]  = exp2v(lrelu(sb[e] + s2c)  + rdenL[i1 * 32 + c]);
            q[8 + e]  = exp2v(lrelu(sc_[e] + s2c) + rdenL[i2i * 32 + c]);
            q[12 + e] = exp2v(lrelu(sd[e] + s2c)  + rdenL[i3 * 32 + c]);
        }
        union { unsigned u[4]; bf16x8 v; } A2_0, A2_1;
        A2_0.u[0] = pk2(q[0], q[1]);   A2_0.u[1] = pk2(q[2], q[3]);
        A2_0.u[2] = pk2(q[4], q[5]);   A2_0.u[3] = pk2(q[6], q[7]);
        A2_1.u[0] = pk2(q[8], q[9]);   A2_1.u[1] = pk2(q[10], q[11]);
        A2_1.u[2] = pk2(q[12], q[13]); A2_1.u[3] = pk2(q[14], q[15]);

        f32x16 d2;
#pragma unroll
        for (int r = 0; r < 16; ++r) d2[r] = 0.f;
        d2 = __builtin_amdgcn_mfma_f32_32x32x16_bf16(A2_0.v, B2f[0], d2, 0, 0, 0);
        d2 = __builtin_amdgcn_mfma_f32_32x32x16_bf16(A2_1.v, B2f[1], d2, 0, 0, 0);
        bf16x8 B3_0 = xform<0>(d2, hi);
        bf16x8 B3_1 = xform<1>(d2, hi);

        // stage 3: D3[f][i2] = sum_j Wh[j][f] M[j][i2]
        f32x16 d3;
#pragma unroll
        for (int r = 0; r < 16; ++r) d3[r] = 0.f;
        d3 = __builtin_amdgcn_mfma_f32_32x32x16_bf16(A3_0, B3_0, d3, 0, 0, 0);
        d3 = __builtin_amdgcn_mfma_f32_32x32x16_bf16(A3_1, B3_1, d3, 0, 0, 0);

        // store: out[(((n*64+w)*64 + f*2+hh5)*32 + f3)*32 + c]
        float* ob = out + (((long)(n * 64 + s) * 64) * 32 + f3) * 32 + c;
#pragma unroll
        for (int r = 0; r < 16; ++r) {
            int f = (r & 3) + 8 * (r >> 2) + 4 * hi;
            __builtin_nontemporal_store(elu(d3[r]), ob + (f * 2 + hh5) * 1024);
        }
    }
}

extern "C" void kernel_launch(void* const* d_in, const int* in_sizes, int n_in,
                              void* d_out, int out_size, void* d_ws, size_t ws_size,
                              hipStream_t stream) {
    (void)in_sizes; (void)n_in; (void)out_size; (void)ws_size;
    const float* hin    = (const float*)d_in[0];
    const float* W_map  = (const float*)d_in[1];
    const float* b_map  = (const float*)d_in[2];
    const float* a_attn = (const float*)d_in[3];
    const float* B_adj  = (const float*)d_in[4];
    float* out = (float*)d_out;
    float* ws  = (float*)d_ws;

    hipLaunchKernelGGL(k0_prep, dim3(1),   dim3(1024), 0, stream, W_map, b_map, a_attn, B_adj, ws);
    hipLaunchKernelGGL(kfused,  dim3(512), dim3(1024), 0, stream, hin, b_map, ws, out);
}

// Round 18
// 64.139 us; speedup vs baseline: 1.5681x; 1.0079x over previous
//
#include <hip/hip_runtime.h>
#include <hip/hip_bf16.h>
#include <math.h>

typedef __attribute__((ext_vector_type(8))) short bf16x8;
typedef __attribute__((ext_vector_type(16))) float f32x16;
typedef __attribute__((ext_vector_type(4))) float f32x4;
typedef __attribute__((ext_vector_type(8))) unsigned short us8;

#define LOG2E 1.4426950408889634f

// ws layout (float offsets)
static constexpr size_t WS_WA   = 0;     // 64: wa1[32] ‖ wa2[32] (k0-internal)
static constexpr size_t WS_C12  = 64;    // 2: (b.a1)*log2e, (b.a2)*log2e
static constexpr size_t WS_WMF  = 96;    // 1024 u16: stage-1 B frags [kap][l][e] = wm[t][f], t=16kap+8(l>>5)+e, f=l&31
static constexpr size_t WS_ADJF = 608;   // 1024 u16: stage-2 B frags (adj_n, same layout)
static constexpr size_t WS_WAB  = 1120;  // 1024 u16: s1/s2 B frags (pre-scaled by log2e): col0=wa1, col1=wa2, else 0

// native 2^x / log2(x) (v_exp_f32 / v_log_f32)
__device__ __forceinline__ float exp2v(float x){ return __builtin_amdgcn_exp2f(x); }
__device__ __forceinline__ float log2v(float x){ return __builtin_amdgcn_logf(x); }

// manual RNE pack (k0 only — cold)
__device__ __forceinline__ unsigned short f2bf(float x){
    union { float f; unsigned u; } c; c.f = x;
    unsigned r = c.u + 0x7FFFu + ((c.u >> 16) & 1u);
    return (unsigned short)(r >> 16);
}
// hot pack: native packed f32x2 -> bf16x2 (RNE) via hip_bf16 — compiler emits
// v_cvt_pk_bf16_f32 (1 VALU op vs ~12 for the manual pair)
__device__ __forceinline__ unsigned pk2(float a, float b){
    __hip_bfloat162 h = __float22bfloat162_rn(make_float2(a, b));
    union { __hip_bfloat162 h; unsigned u; } cv; cv.h = h; return cv.u;
}
__device__ __forceinline__ float bf2f(unsigned short v){
    return __uint_as_float(((unsigned)v) << 16);
}
__device__ __forceinline__ float elu(float x){ return x > 0.f ? x : __expf(x) - 1.0f; }
__device__ __forceinline__ float lrelu(float x){ return fmaxf(x, 0.2f * x); }

__global__ __launch_bounds__(1024) void k0_prep(const float* __restrict__ W_map,
    const float* __restrict__ b_map, const float* __restrict__ a_attn,
    const float* __restrict__ B_adj, float* __restrict__ ws)
{
    __shared__ float lds[1024];
    __shared__ float d12[32];
    __shared__ float waS[64];
    int tid = threadIdx.x;
    int i = tid >> 5, j = tid & 31;
    float a = B_adj[tid] + (i == j ? 1.0f : 0.0f);
    lds[tid] = a; __syncthreads();
    for (int s = 512; s > 0; s >>= 1) { if (tid < s) lds[tid] = fmaxf(lds[tid], lds[tid + s]); __syncthreads(); }
    float mx = lds[0]; __syncthreads();
    lds[tid] = a; __syncthreads();
    for (int s = 512; s > 0; s >>= 1) { if (tid < s) lds[tid] = fminf(lds[tid], lds[tid + s]); __syncthreads(); }
    float mn = lds[0]; __syncthreads();
    lds[tid] = (a - mn) / (mx - mn); __syncthreads();
    if (tid < 32) {
        float s = 0.f;
        for (int jj = 0; jj < 32; ++jj) s += lds[tid * 32 + jj];
        d12[tid] = 1.0f / sqrtf(s);
    }
    if (tid < 32) {
        float w1 = 0.f, w2 = 0.f;
        for (int f = 0; f < 32; ++f) {
            w1 += W_map[tid * 32 + f] * a_attn[f];
            w2 += W_map[tid * 32 + f] * a_attn[32 + f];
        }
        waS[tid] = w1; waS[32 + tid] = w2;
        ws[WS_WA + tid] = w1; ws[WS_WA + 32 + tid] = w2;
    }
    __syncthreads();

    // frag-ordered constants: idx = kap*512 + l*8 + e
    {
        int kap = tid >> 9, rem = tid & 511, l = rem >> 3, e = rem & 7;
        int krow = 16 * kap + 8 * (l >> 5) + e;   // t (for wm) / i (for adj) / k (for wa)
        int col  = l & 31;                        // f / i2
        ((unsigned short*)(ws + WS_WMF))[tid] = f2bf(W_map[krow * 32 + col]);
        float aij = B_adj[krow * 32 + col] + (krow == col ? 1.0f : 0.0f);
        float adjv = d12[krow] * ((aij - mn) / (mx - mn)) * d12[col];
        ((unsigned short*)(ws + WS_ADJF))[tid] = f2bf(adjv);
        // pre-scale by log2e: downstream softmax runs in log2 domain
        float wab = (col == 0) ? waS[krow] * LOG2E : (col == 1) ? waS[32 + krow] * LOG2E : 0.f;
        ((unsigned short*)(ws + WS_WAB))[tid] = f2bf(wab);
    }
    if (tid == 0) {
        float c1 = 0.f, c2 = 0.f;
        for (int f = 0; f < 32; ++f) { c1 += b_map[f] * a_attn[f]; c2 += b_map[f] * a_attn[32 + f]; }
        ws[WS_C12] = c1 * LOG2E; ws[WS_C12 + 1] = c2 * LOG2E;
    }
}

// D(32x32 mfma, col=l&31) -> next-stage A/B frag (idx=l&31, k=16*KAP+8*(l>>5)+e).
#if __has_builtin(__builtin_amdgcn_permlane32_swap)
typedef __attribute__((ext_vector_type(2))) unsigned int u32p;
template<int KAP>
__device__ __forceinline__ bf16x8 xform(const f32x16& d, int hi){
    (void)hi;
    unsigned b0 = pk2(d[8*KAP+0], d[8*KAP+1]);
    unsigned b1 = pk2(d[8*KAP+2], d[8*KAP+3]);
    unsigned b2 = pk2(d[8*KAP+4], d[8*KAP+5]);
    unsigned b3 = pk2(d[8*KAP+6], d[8*KAP+7]);
    u32p s02 = __builtin_amdgcn_permlane32_swap(b0, b2, false, false);
    u32p s13 = __builtin_amdgcn_permlane32_swap(b1, b3, false, false);
    union { unsigned u[4]; bf16x8 v; } t;
    t.u[0] = s02[0]; t.u[1] = s13[0]; t.u[2] = s02[1]; t.u[3] = s13[1];
    return t.v;
}
#else
template<int KAP>
__device__ __forceinline__ bf16x8 xform(const f32x16& d, int hi){
    unsigned b0 = pk2(d[8*KAP+0], d[8*KAP+1]);
    unsigned b1 = pk2(d[8*KAP+2], d[8*KAP+3]);
    unsigned b2 = pk2(d[8*KAP+4], d[8*KAP+5]);
    unsigned b3 = pk2(d[8*KAP+6], d[8*KAP+7]);
    unsigned pb0 = (unsigned)__shfl_xor((int)b0, 32, 64);
    unsigned pb1 = (unsigned)__shfl_xor((int)b1, 32, 64);
    unsigned pb2 = (unsigned)__shfl_xor((int)b2, 32, 64);
    unsigned pb3 = (unsigned)__shfl_xor((int)b3, 32, 64);
    union { unsigned u[4]; bf16x8 v; } t;
    t.u[0] = hi ? pb2 : b0;
    t.u[1] = hi ? pb3 : b1;
    t.u[2] = hi ? b2 : pb0;
    t.u[3] = hi ? b3 : pb1;
    return t.v;
}
#endif

// One block = one (n,hh) row. h staged once (bf16 frag order, conflict-free);
// s1/s2 via MFMA (log2-scaled); rden as -log2(den); 3 chained MFMA stages; NT stores.
__global__ __launch_bounds__(1024, 4) void kfused(const float* __restrict__ hin,
    const float* __restrict__ b_map, const float* __restrict__ ws, float* __restrict__ out)
{
    __shared__ unsigned short hbf[64 * 1024];   // 128 KB: [s][kap][v+32hw][e]
    __shared__ float s1L[64 * 32];              // 8 KB  [w][i]  (log2-scaled)
    __shared__ float s2L[64 * 32];              // 8 KB
    __shared__ float rdenL[1024];               // 4 KB  [i][j] = -log2(den)

    const int tid = threadIdx.x;
    const int wv = tid >> 6, l = tid & 63;
    const int c = l & 31, hi = l >> 5;
    const int nh = blockIdx.x;                  // n*64 + hh
    const int hh = nh & 63, n = nh >> 6;

    const float c1 = ws[WS_C12], c2 = ws[WS_C12 + 1];
    const float bc = b_map[c];

    bf16x8 B1f[2], B2f[2], WaB[2];
    {
        const unsigned short* wmf = (const unsigned short*)(ws + WS_WMF);
        const unsigned short* adf = (const unsigned short*)(ws + WS_ADJF);
        const unsigned short* wab = (const unsigned short*)(ws + WS_WAB);
        B1f[0] = *(const bf16x8*)(wmf + l * 8);
        B1f[1] = *(const bf16x8*)(wmf + 512 + l * 8);
        B2f[0] = *(const bf16x8*)(adf + l * 8);
        B2f[1] = *(const bf16x8*)(adf + 512 + l * 8);
        WaB[0] = *(const bf16x8*)(wab + l * 8);
        WaB[1] = *(const bf16x8*)(wab + 512 + l * 8);
    }

    // ---- phase A: stage row -> hbf. 8 stride-32 scalar loads (128B coalesced)
    // -> one contiguous ds_write_b128. Zero conflicts. ----
    {
        const float* hrow = hin + (long)nh * 65536;
        const int v = tid & 31;
#pragma unroll
        for (int it = 0; it < 8; ++it) {
            const int gid = it * 32 + (tid >> 5);           // 0..255
            const int site = gid >> 2, kap = (gid >> 1) & 1, hw = gid & 1;
            const float* hp = hrow + site * 1024 + (16 * kap + 8 * hw) * 32 + v;
            float x[8];
#pragma unroll
            for (int e = 0; e < 8; ++e) x[e] = hp[e * 32];
            union { unsigned u[4]; us8 v8; } pk;
            pk.u[0] = pk2(x[0], x[1]); pk.u[1] = pk2(x[2], x[3]);
            pk.u[2] = pk2(x[4], x[5]); pk.u[3] = pk2(x[6], x[7]);
            *(us8*)(hbf + site * 1024 + kap * 512 + (v + 32 * hw) * 8) = pk.v8;
        }
    }
    __syncthreads();

    // ---- phase A2: s1/s2 via MFMA (log2-scaled). Lanes c<2 write to s1L/s2L. ----
    {
#pragma unroll
        for (int k = 0; k < 4; ++k) {
            const int s = wv * 4 + k;
            const unsigned short* fp = hbf + s * 1024;
            bf16x8 a10 = *(const bf16x8*)(fp + l * 8);
            bf16x8 a11 = *(const bf16x8*)(fp + 512 + l * 8);
            f32x16 ds;
#pragma unroll
            for (int r = 0; r < 16; ++r) ds[r] = 0.f;
            ds = __builtin_amdgcn_mfma_f32_32x32x16_bf16(a10, WaB[0], ds, 0, 0, 0);
            ds = __builtin_amdgcn_mfma_f32_32x32x16_bf16(a11, WaB[1], ds, 0, 0, 0);
            if (c < 2) {
                const float cc = (c == 0) ? c1 : c2;
                float* dst = (c == 0) ? s1L : s2L;
#pragma unroll
                for (int r = 0; r < 16; ++r) {
                    int row = (r & 3) + 8 * (r >> 2) + 4 * hi;
                    dst[s * 32 + row] = ds[r] + cc;
                }
            }
        }
    }
    __syncthreads();

    // ---- phase B: rden[i][j] = -log2( sum_w 2^lrelu(s1'[w,i]+s2'[w,j]) ) ----
    {
        int i = tid >> 5, j = tid & 31;
        float sum = 0.f;
#pragma unroll
        for (int w = 0; w < 64; ++w)
            sum += exp2v(lrelu(s1L[w * 32 + i] + s2L[w * 32 + j]));
        rdenL[tid] = -log2v(sum);
    }
    __syncthreads();

    // ---- phase C: per site, 3 chained 32x32 matmuls, NT stores ----
    const int hh5 = hh >> 5, f3 = hh & 31;
#pragma unroll 2
    for (int k = 0; k < 4; ++k) {
        const int s = wv * 4 + k;
        const unsigned short* fp = hbf + s * 1024;
        bf16x8 a10 = *(const bf16x8*)(fp + l * 8);
        bf16x8 a11 = *(const bf16x8*)(fp + 512 + l * 8);

        // stage 1: D1[j][f] = sum_t h[t][j] wm[t][f] + b[f]
        f32x16 d1;
#pragma unroll
        for (int r = 0; r < 16; ++r) d1[r] = bc;
        d1 = __builtin_amdgcn_mfma_f32_32x32x16_bf16(a10, B1f[0], d1, 0, 0, 0);
        d1 = __builtin_amdgcn_mfma_f32_32x32x16_bf16(a11, B1f[1], d1, 0, 0, 0);
        bf16x8 A3_0 = xform<0>(d1, hi);
        bf16x8 A3_1 = xform<1>(d1, hi);

        // stage 2: attn = 2^( lrelu(s1'+s2') + lrden )  (all log2-domain)
        const float s2c = s2L[s * 32 + c];
        f32x4 sa  = *(const f32x4*)&s1L[s * 32 + 8 * hi];
        f32x4 sb  = *(const f32x4*)&s1L[s * 32 + 8 * hi + 4];
        f32x4 sc_ = *(const f32x4*)&s1L[s * 32 + 16 + 8 * hi];
        f32x4 sd  = *(const f32x4*)&s1L[s * 32 + 16 + 8 * hi + 4];
        float q[16];
#pragma unroll
        for (int e = 0; e < 4; ++e) {
            int i0 = 8 * hi + e, i1 = 8 * hi + 4 + e, i2i = 16 + 8 * hi + e, i3 = 16 + 8 * hi + 4 + e;
            q[e]      = exp2v(lrelu(sa[e] + s2c)  + rdenL[i0 * 32 + c]);
            q[4 + e]  = exp2v(lrelu(sb[e] + s2c)  + rdenL[i1 * 32 + c]);
            q[8 + e]  = exp2v(lrelu(sc_[e] + s2c) + rdenL[i2i * 32 + c]);
            q[12 + e] = exp2v(lrelu(sd[e] + s2c)  + rdenL[i3 * 32 + c]);
        }
        union { unsigned u[4]; bf16x8 v; } A2_0, A2_1;
        A2_0.u[0] = pk2(q[0], q[1]);   A2_0.u[1] = pk2(q[2], q[3]);
        A2_0.u[2] = pk2(q[4], q[5]);   A2_0.u[3] = pk2(q[6], q[7]);
        A2_1.u[0] = pk2(q[8], q[9]);   A2_1.u[1] = pk2(q[10], q[11]);
        A2_1.u[2] = pk2(q[12], q[13]); A2_1.u[3] = pk2(q[14], q[15]);

        f32x16 d2;
#pragma unroll
        for (int r = 0; r < 16; ++r) d2[r] = 0.f;
        d2 = __builtin_amdgcn_mfma_f32_32x32x16_bf16(A2_0.v, B2f[0], d2, 0, 0, 0);
        d2 = __builtin_amdgcn_mfma_f32_32x32x16_bf16(A2_1.v, B2f[1], d2, 0, 0, 0);
        bf16x8 B3_0 = xform<0>(d2, hi);
        bf16x8 B3_1 = xform<1>(d2, hi);

        // stage 3: D3[f][i2] = sum_j Wh[j][f] M[j][i2]
        f32x16 d3;
#pragma unroll
        for (int r = 0; r < 16; ++r) d3[r] = 0.f;
        d3 = __builtin_amdgcn_mfma_f32_32x32x16_bf16(A3_0, B3_0, d3, 0, 0, 0);
        d3 = __builtin_amdgcn_mfma_f32_32x32x16_bf16(A3_1, B3_1, d3, 0, 0, 0);

        // store: out[(((n*64+w)*64 + f*2+hh5)*32 + f3)*32 + c]
        float* ob = out + (((long)(n * 64 + s) * 64) * 32 + f3) * 32 + c;
#pragma unroll
        for (int r = 0; r < 16; ++r) {
            int f = (r & 3) + 8 * (r >> 2) + 4 * hi;
            __builtin_nontemporal_store(elu(d3[r]), ob + (f * 2 + hh5) * 1024);
        }
    }
}

extern "C" void kernel_launch(void* const* d_in, const int* in_sizes, int n_in,
                              void* d_out, int out_size, void* d_ws, size_t ws_size,
                              hipStream_t stream) {
    (void)in_sizes; (void)n_in; (void)out_size; (void)ws_size;
    const float* hin    = (const float*)d_in[0];
    const float* W_map  = (const float*)d_in[1];
    const float* b_map  = (const float*)d_in[2];
    const float* a_attn = (const float*)d_in[3];
    const float* B_adj  = (const float*)d_in[4];
    float* out = (float*)d_out;
    float* ws  = (float*)d_ws;

    hipLaunchKernelGGL(k0_prep, dim3(1),   dim3(1024), 0, stream, W_map, b_map, a_attn, B_adj, ws);
    hipLaunchKernelGGL(kfused,  dim3(512), dim3(1024), 0, stream, hin, b_map, ws, out);
}